// Round 5
// baseline (272.345 us; speedup 1.0000x reference)
//
#include <hip/hip_runtime.h>
#include <math.h>

#define NB 32              // batches per 512-thread block
#define SLAB_F 4096        // slab = 2 W-rows x 2048 floats = 16 KB
#define NSLAB 64           // 128 k-rows / 2 per slab

// R5: = R4 (conflict-free rotation, LDS-staged W, reg-LU) + packed-FP32
// accumulation. The gather was VALU-issue-bound (71% VALUBusy; divergent
// walk ~72 iters/wave x 32 scalar v_add). v_pk_add_f32 (VOP3P, gfx90a+)
// halves the add instruction count: accumulators are f32x2 pairs, the
// ds_read_b128 result feeds the asm via free .lo/.hi subregister halves.
// IEEE add semantics identical -> bitwise-same sums.
//  - rotation: step c reads physical chunk (c+s8)&3 -> 8 lanes/bank-quad
//    per slot = zero conflicts; predicated un-rotation before LU.
//  - phase 1: 16 lanes/batch -> sorted occupied-k lists (slot 32 sentinel).
//  - main loop: 64 slabs double-buffered via global_load_lds (linear).
//  - LU: 8-lane implicit-partial-pivot on accumulator regs.

typedef float f32x2 __attribute__((ext_vector_type(2)));
typedef float f32x4 __attribute__((ext_vector_type(4)));

#define GLD_LDS16(gp, lp) __builtin_amdgcn_global_load_lds( \
    (const __attribute__((address_space(1))) void*)(gp),    \
    (__attribute__((address_space(3))) void*)(lp), 16, 0, 0)

// acc (f32x2 pair) += half of a b128 load, as one packed add
#define PKADD(acc, half) asm("v_pk_add_f32 %0, %0, %1" : "+v"(acc) : "v"(half))

__global__ __launch_bounds__(512, 4) void backflow_kernel(
    const int* __restrict__ nocc,   // (B,128) int32 0/1
    const float* __restrict__ W,    // (128,2048) f32 row-major
    float* __restrict__ out,        // planar: [B re][B im]
    int B)
{
    __shared__ float slab[2 * SLAB_F];   // 32 KB double buffer
    __shared__ int lists[NB][33];        // 4.2 KB; slot 32 = sentinel

    const int tid = threadIdx.x;

    // ---------------- phase 1: occupancy -> k lists ----------------
    {
        const int bib1 = tid >> 4;                 // 0..31
        const int l16  = tid & 15;
        int batch1 = blockIdx.x * NB + bib1;
        if (batch1 >= B) batch1 = B - 1;
        const int4* np = reinterpret_cast<const int4*>(nocc + (size_t)batch1 * 128 + l16 * 8);
        int4 v0 = np[0];
        int4 v1 = np[1];
        unsigned nib = 0;
        nib |= (v0.x != 0) ? 1u   : 0u;
        nib |= (v0.y != 0) ? 2u   : 0u;
        nib |= (v0.z != 0) ? 4u   : 0u;
        nib |= (v0.w != 0) ? 8u   : 0u;
        nib |= (v1.x != 0) ? 16u  : 0u;
        nib |= (v1.y != 0) ? 32u  : 0u;
        nib |= (v1.z != 0) ? 64u  : 0u;
        nib |= (v1.w != 0) ? 128u : 0u;
        const int cnt = __popc(nib);
        int incl = cnt;
        const int seg = l16 & 7;
        #pragma unroll
        for (int d = 1; d < 8; d <<= 1) {
            int t = __shfl_up(incl, d, 8);
            if (seg >= d) incl += t;
        }
        int pos = ((l16 >> 3) << 4) + (incl - cnt);
        const int k0 = l16 * 8;
        #pragma unroll
        for (int b = 0; b < 8; b++) {
            if (nib & (1u << b)) lists[bib1][pos++] = k0 + b;
        }
        if (l16 == 0) lists[bib1][32] = 1 << 30;   // sentinel for k-walk
    }
    __syncthreads();

    // ---------------- thread ids (LU layout from the start) ----------------
    const int lane = tid & 63;
    const int wv   = __builtin_amdgcn_readfirstlane(tid >> 6);  // 0..7, SGPR
    const int g    = lane >> 3;         // 0..7
    const int s8   = lane & 7;
    const int m    = g & 1;             // 0 = up, 1 = dn
    const int bib  = (wv << 2) + (g >> 1);   // 0..31
    int batch = blockIdx.x * NB + bib;
    const bool valid = (batch < B);
    if (!valid) batch = B - 1;

    // ---------------- staging setup (linear source & dest) ----------------
    const int col_l = (wv << 8) + (lane << 2);            // float idx within k-row
    const char* gp0 = (const char*)(W + col_l);           // k row 0 of slab
    const char* gp1 = (const char*)(W + 2048 + col_l);    // k row 1 of slab
    char* const lb_base = (char*)slab + (wv << 10);       // wave-uniform dest

    // prologue: stage slab 0 (k rows 0,1) into buffer 0
    GLD_LDS16(gp0, lb_base);
    GLD_LDS16(gp1, lb_base + 8192);
    gp0 += 16384; gp1 += 16384;

    // my two A-rows: orbital indices within spin block
    const int* lp = lists[bib];
    const int r0 = lp[(m << 4) + s8] - (m << 6);
    const int r1 = lp[(m << 4) + s8 + 8] - (m << 6);
    // rotated chunk offsets: step c reads physical chunk (c+s8)&3
    int off0[4], off1[4];
    #pragma unroll
    for (int c = 0; c < 4; c++) {
        const int cc = (c + s8) & 3;
        off0[c] = (r0 << 5) + (m << 4) + (cc << 2);
        off1[c] = (r1 << 5) + (m << 4) + (cc << 2);
    }

    f32x2 a0p[8] = {};   // block c lives in a0p[2c], a0p[2c+1]
    f32x2 a1p[8] = {};

    int ptr = 0;
    int nk = lp[0];

    __syncthreads();   // slab 0 resident (compiler drains vmcnt before barrier)

    // ---------------- main loop: stage next, gather current ----------------
    #pragma unroll 1
    for (int s = 0; s < NSLAB; s++) {
        if (s < NSLAB - 1) {
            char* lb = (char*)slab + (((s + 1) & 1) << 14) + (wv << 10);
            GLD_LDS16(gp0, lb);
            GLD_LDS16(gp1, lb + 8192);
            gp0 += 16384; gp1 += 16384;
        }
        const float* cp = slab + ((s & 1) ? SLAB_F : 0);
        const int kend = (s << 1) + 2;
        while (nk < kend) {
            const float* kp = cp + ((nk & 1) << 11);   // k-local row in slab
            f32x4 v;
            v = *reinterpret_cast<const f32x4*>(kp + off0[0]);
            PKADD(a0p[0], v.lo);  PKADD(a0p[1], v.hi);
            v = *reinterpret_cast<const f32x4*>(kp + off0[1]);
            PKADD(a0p[2], v.lo);  PKADD(a0p[3], v.hi);
            v = *reinterpret_cast<const f32x4*>(kp + off0[2]);
            PKADD(a0p[4], v.lo);  PKADD(a0p[5], v.hi);
            v = *reinterpret_cast<const f32x4*>(kp + off0[3]);
            PKADD(a0p[6], v.lo);  PKADD(a0p[7], v.hi);
            v = *reinterpret_cast<const f32x4*>(kp + off1[0]);
            PKADD(a1p[0], v.lo);  PKADD(a1p[1], v.hi);
            v = *reinterpret_cast<const f32x4*>(kp + off1[1]);
            PKADD(a1p[2], v.lo);  PKADD(a1p[3], v.hi);
            v = *reinterpret_cast<const f32x4*>(kp + off1[2]);
            PKADD(a1p[4], v.lo);  PKADD(a1p[5], v.hi);
            v = *reinterpret_cast<const f32x4*>(kp + off1[3]);
            PKADD(a1p[6], v.lo);  PKADD(a1p[7], v.hi);
            ptr++;
            nk = lp[ptr];   // slot 32 = sentinel
        }
        __syncthreads();
    }

    // ---------------- un-rotate accumulator blocks (one-time) ----------------
    // block c holds physical chunk (c+s8)&3; right-rotate blocks by s8&3
    // (two predicated stages, all static indices). block c = pairs {2c,2c+1}.
    {
        const bool rb1 = (s8 & 1) != 0;
        const bool rb2 = (s8 & 2) != 0;
        f32x2 t[8];
        #pragma unroll
        for (int e = 0; e < 2; e++) {
            t[0 + e] = rb1 ? a0p[6 + e] : a0p[0 + e];
            t[2 + e] = rb1 ? a0p[0 + e] : a0p[2 + e];
            t[4 + e] = rb1 ? a0p[2 + e] : a0p[4 + e];
            t[6 + e] = rb1 ? a0p[4 + e] : a0p[6 + e];
        }
        #pragma unroll
        for (int e = 0; e < 2; e++) {
            a0p[0 + e] = rb2 ? t[4 + e] : t[0 + e];
            a0p[2 + e] = rb2 ? t[6 + e] : t[2 + e];
            a0p[4 + e] = rb2 ? t[0 + e] : t[4 + e];
            a0p[6 + e] = rb2 ? t[2 + e] : t[6 + e];
        }
        #pragma unroll
        for (int e = 0; e < 2; e++) {
            t[0 + e] = rb1 ? a1p[6 + e] : a1p[0 + e];
            t[2 + e] = rb1 ? a1p[0 + e] : a1p[2 + e];
            t[4 + e] = rb1 ? a1p[2 + e] : a1p[4 + e];
            t[6 + e] = rb1 ? a1p[4 + e] : a1p[6 + e];
        }
        #pragma unroll
        for (int e = 0; e < 2; e++) {
            a1p[0 + e] = rb2 ? t[4 + e] : t[0 + e];
            a1p[2 + e] = rb2 ? t[6 + e] : t[2 + e];
            a1p[4 + e] = rb2 ? t[0 + e] : t[4 + e];
            a1p[6 + e] = rb2 ? t[2 + e] : t[6 + e];
        }
    }

    // ---------------- LU, implicit partial pivoting (on accum regs) ----------------
    #define A0(k) a0p[(k) >> 1][(k) & 1]
    #define A1(k) a1p[(k) >> 1][(k) & 1]

    unsigned active = 0xffffu;
    int inv = 0;
    float myd0 = 1.f, myd1 = 1.f;

    #pragma unroll
    for (int k = 0; k < 16; k++) {
        const unsigned act0 = (active >> s8) & 1u;
        const unsigned act1 = (active >> (s8 + 8)) & 1u;
        float av = act0 ? fabsf(A0(k)) : -1.f;
        int idx = s8;
        {
            float av1 = act1 ? fabsf(A1(k)) : -1.f;
            if (av1 > av) { av = av1; idx = s8 + 8; }
        }
        #pragma unroll
        for (int d = 1; d < 8; d <<= 1) {
            float ov = __shfl_xor(av, d, 8);
            int   oi = __shfl_xor(idx, d, 8);
            if (ov > av || (ov == av && oi < idx)) { av = ov; idx = oi; }
        }
        const int p = idx;
        const int plane = p & 7;
        const bool phi = (p & 8) != 0;
        float psel = phi ? A1(k) : A0(k);
        const float pk = __shfl(psel, plane, 8);
        const float rcp = 1.0f / pk;

        if (s8 == p)     myd0 = pk;
        if (s8 + 8 == p) myd1 = pk;
        inv += __popc(active & ((1u << p) - 1u));
        active &= ~(1u << p);

        const float f0 = (act0 && s8 != p)       ? A0(k) * rcp : 0.f;
        const float f1 = (act1 && (s8 + 8) != p) ? A1(k) * rcp : 0.f;

        #pragma unroll
        for (int j = k + 1; j < 16; j++) {
            float sel = phi ? A1(j) : A0(j);
            float pv = __shfl(sel, plane, 8);
            A0(j) = fmaf(-f0, pv, A0(j));
            A1(j) = fmaf(-f1, pv, A1(j));
        }
    }

    float ld = logf(fabsf(myd0)) + logf(fabsf(myd1));
    int ng = ((myd0 < 0.f) ? 1 : 0) + ((myd1 < 0.f) ? 1 : 0);
    #pragma unroll
    for (int d = 1; d < 8; d <<= 1) {
        ld += __shfl_xor(ld, d, 8);
        ng += __shfl_xor(ng, d, 8);
    }
    const int neg = (ng + inv) & 1;

    const float ld_o  = __shfl_xor(ld, 8, 16);
    const int   neg_o = __shfl_xor(neg, 8, 16);

    if ((lane & 15) == 0 && valid) {
        out[batch]     = ld + ld_o;                                      // re plane
        out[B + batch] = 3.14159265358979323846f * (float)(neg + neg_o); // im plane
    }
}

extern "C" void kernel_launch(void* const* d_in, const int* in_sizes, int n_in,
                              void* d_out, int out_size, void* d_ws, size_t ws_size,
                              hipStream_t stream) {
    const int* nocc = (const int*)d_in[0];
    const float* W  = (const float*)d_in[1];
    float* out = (float*)d_out;
    const int B = in_sizes[0] / 128;                 // 65536
    const int blocks = (B + NB - 1) / NB;            // 2048
    backflow_kernel<<<blocks, 512, 0, stream>>>(nocc, W, out, B);
}

// Round 7
// 261.229 us; speedup vs baseline: 1.0426x; 1.0426x over previous
//
#include <hip/hip_runtime.h>
#include <math.h>

#define NB 32              // batches per 512-thread block
#define SLAB_F 4096        // slab = 2 W-rows x 2048 floats = 16 KB
#define NSLAB 64           // 128 k-rows / 2 per slab
#define UNI_F 10240        // union: max(2*SLAB_F=8192, 8 waves*2*32*20=10240) floats

// R6 (resubmit; prior run failed at container level, no kernel diagnostic).
// Full-wave gather. R5 was LDS-issue-bound: divergent 4-batch lock-step
// walk issued 8 partially-masked b128 per max-iter (~44% lane activity,
// 36.8K issues/CU). Now ONE wave serves ONE batch's one occupied k per
// iteration: lane=(row 0..31, half 0..1) owns 8 floats; 2 full-activity
// ds_read_b128 per k = the 512-float minimum. Waves walk their 4 batches
// sequentially (sum=128 iters, all full activity) -> 16.4K issues/CU.
//  - conflict-free: chunk order cc = c ^ (row&1): bank-quad m*4+h*2+cc
//    uniform 8 lanes/quad per slot.
//  - LU transpose via per-wave LDS scratch REUSING the slab union (41 KB
//    total, 3 blocks/CU), 2 batches/pass, wave-local lgkmcnt waits only
//    (+ sched_barrier(0) guards per rule #18).
//    Rotation resolved at scratch-write address (no un-rotate pass).
//  - phase 1 lists + LU (8-lane implicit partial pivot) unchanged.

typedef float f32x2 __attribute__((ext_vector_type(2)));
typedef float f32x4 __attribute__((ext_vector_type(4)));

#define GLD_LDS16(gp, lp) __builtin_amdgcn_global_load_lds( \
    (const __attribute__((address_space(1))) void*)(gp),    \
    (__attribute__((address_space(3))) void*)(lp), 16, 0, 0)

// acc (f32x2) += half of a b128 load, one packed add (IEEE-identical)
#define PKADD(acc, half) asm("v_pk_add_f32 %0, %0, %1" : "+v"(acc) : "v"(half))

__global__ __launch_bounds__(512, 4) void backflow_kernel(
    const int* __restrict__ nocc,   // (B,128) int32 0/1
    const float* __restrict__ W,    // (128,2048) f32 row-major
    float* __restrict__ out,        // planar: [B re][B im]
    int B)
{
    __shared__ __align__(16) float uni[UNI_F];   // slab dbuf, later scratch
    __shared__ int lists[NB][33];                // slot 32 = sentinel

    const int tid = threadIdx.x;

    // ---------------- phase 1: occupancy -> k lists ----------------
    {
        const int bib1 = tid >> 4;                 // 0..31
        const int l16  = tid & 15;
        int batch1 = blockIdx.x * NB + bib1;
        if (batch1 >= B) batch1 = B - 1;
        const int4* np = reinterpret_cast<const int4*>(nocc + (size_t)batch1 * 128 + l16 * 8);
        int4 v0 = np[0];
        int4 v1 = np[1];
        unsigned nib = 0;
        nib |= (v0.x != 0) ? 1u   : 0u;
        nib |= (v0.y != 0) ? 2u   : 0u;
        nib |= (v0.z != 0) ? 4u   : 0u;
        nib |= (v0.w != 0) ? 8u   : 0u;
        nib |= (v1.x != 0) ? 16u  : 0u;
        nib |= (v1.y != 0) ? 32u  : 0u;
        nib |= (v1.z != 0) ? 64u  : 0u;
        nib |= (v1.w != 0) ? 128u : 0u;
        const int cnt = __popc(nib);
        int incl = cnt;
        const int seg = l16 & 7;
        #pragma unroll
        for (int d = 1; d < 8; d <<= 1) {
            int t = __shfl_up(incl, d, 8);
            if (seg >= d) incl += t;
        }
        int pos = ((l16 >> 3) << 4) + (incl - cnt);
        const int k0 = l16 * 8;
        #pragma unroll
        for (int b = 0; b < 8; b++) {
            if (nib & (1u << b)) lists[bib1][pos++] = k0 + b;
        }
        if (l16 == 0) lists[bib1][32] = 1 << 30;   // sentinel
    }
    __syncthreads();

    // ---------------- ids ----------------
    const int lane = tid & 63;
    const int wv   = __builtin_amdgcn_readfirstlane(tid >> 6);  // 0..7
    const int wb0  = wv << 2;            // first batch-in-block of this wave

    // gather decomposition: lane owns (row rowidx, half h) of each batch's A
    const int rowidx = lane >> 1;        // 0..31 (0..15 up, 16..31 dn)
    const int h      = lane & 1;         // 8-float half of the 16-col row
    const int m2     = rowidx >> 4;      // spin of owned row
    const int rot    = rowidx & 1;       // chunk-parity rotation key

    // ---------------- staging setup (linear, unchanged) ----------------
    const int col_l = (wv << 8) + (lane << 2);
    const char* gp0 = (const char*)(W + col_l);
    const char* gp1 = (const char*)(W + 2048 + col_l);
    char* const lb_base = (char*)uni + (wv << 10);

    GLD_LDS16(gp0, lb_base);            // prologue: slab 0 -> buffer 0
    GLD_LDS16(gp1, lb_base + 8192);
    gp0 += 16384; gp1 += 16384;

    // per-batch row offsets (bytes within one staged k-row) + walk state
    int offs[4][2];
    int ptr4[4], nk4[4];
    #pragma unroll
    for (int b = 0; b < 4; b++) {
        const int ro = lists[wb0 + b][rowidx] - (m2 << 6);   // 0..63
        offs[b][0] = (ro << 7) + (m2 << 6) + (h << 5) + ((0 ^ rot) << 4);
        offs[b][1] = (ro << 7) + (m2 << 6) + (h << 5) + ((1 ^ rot) << 4);
        ptr4[b] = 0;
        nk4[b] = lists[wb0 + b][0];
    }

    f32x2 acc[4][4] = {};   // [batch][2*slot+e]; slot c = physical chunk c^rot

    __syncthreads();   // slab 0 resident

    // ---------------- main loop: stage next, gather current ----------------
    #pragma unroll 1
    for (int s = 0; s < NSLAB; s++) {
        if (s < NSLAB - 1) {
            char* lb = (char*)uni + (((s + 1) & 1) << 14) + (wv << 10);
            GLD_LDS16(gp0, lb);
            GLD_LDS16(gp1, lb + 8192);
            gp0 += 16384; gp1 += 16384;
        }
        const char* cpB = (const char*)uni + ((s & 1) << 14);
        const int kend = (s << 1) + 2;
        #pragma unroll
        for (int b = 0; b < 4; b++) {
            while (nk4[b] < kend) {
                const char* kp = cpB + ((nk4[b] & 1) << 13);
                f32x4 v0 = *reinterpret_cast<const f32x4*>(kp + offs[b][0]);
                f32x4 v1 = *reinterpret_cast<const f32x4*>(kp + offs[b][1]);
                PKADD(acc[b][0], v0.lo); PKADD(acc[b][1], v0.hi);
                PKADD(acc[b][2], v1.lo); PKADD(acc[b][3], v1.hi);
                ptr4[b]++;
                nk4[b] = lists[wb0 + b][ptr4[b]];
            }
        }
        __syncthreads();
    }
    // final barrier: all waves done with slab -> safe to reuse as scratch

    // ---------------- within-wave transpose via per-wave scratch ----------------
    const int g   = lane >> 3;          // LU group 0..7
    const int s8  = lane & 7;
    const int m   = g & 1;              // 0 = up, 1 = dn
    const int bwl = g >> 1;             // batch-in-wave 0..3
    int batch = blockIdx.x * NB + wb0 + bwl;
    const bool valid = (batch < B);
    if (!valid) batch = B - 1;

    float* const sw = uni + wv * 1280;          // [2 batches][32 rows][20]
    float* const wr = sw + rowidx * 20 + (h << 3);
    float a0[16], a1[16];

    // pass A: write batches 0,1; LU-read for lanes 0..31 (groups 0..3)
    {
        f32x4 t;
        t.lo = acc[0][0]; t.hi = acc[0][1];
        *reinterpret_cast<f32x4*>(wr + ((0 ^ rot) << 2)) = t;
        t.lo = acc[0][2]; t.hi = acc[0][3];
        *reinterpret_cast<f32x4*>(wr + ((1 ^ rot) << 2)) = t;
        t.lo = acc[1][0]; t.hi = acc[1][1];
        *reinterpret_cast<f32x4*>(wr + 640 + ((0 ^ rot) << 2)) = t;
        t.lo = acc[1][2]; t.hi = acc[1][3];
        *reinterpret_cast<f32x4*>(wr + 640 + ((1 ^ rot) << 2)) = t;
    }
    asm volatile("s_waitcnt lgkmcnt(0)" ::: "memory");
    __builtin_amdgcn_sched_barrier(0);
    if (lane < 32) {
        const float* r0 = sw + bwl * 640 + (m * 16 + s8) * 20;
        const float* r1 = r0 + 160;
        #pragma unroll
        for (int qq = 0; qq < 4; qq++) {
            f32x4 u0 = *reinterpret_cast<const f32x4*>(r0 + qq * 4);
            f32x4 u1 = *reinterpret_cast<const f32x4*>(r1 + qq * 4);
            a0[qq*4+0] = u0.x; a0[qq*4+1] = u0.y; a0[qq*4+2] = u0.z; a0[qq*4+3] = u0.w;
            a1[qq*4+0] = u1.x; a1[qq*4+1] = u1.y; a1[qq*4+2] = u1.z; a1[qq*4+3] = u1.w;
        }
    }
    asm volatile("s_waitcnt lgkmcnt(0)" ::: "memory");
    __builtin_amdgcn_sched_barrier(0);
    // pass B: overwrite with batches 2,3; LU-read for lanes 32..63
    {
        f32x4 t;
        t.lo = acc[2][0]; t.hi = acc[2][1];
        *reinterpret_cast<f32x4*>(wr + ((0 ^ rot) << 2)) = t;
        t.lo = acc[2][2]; t.hi = acc[2][3];
        *reinterpret_cast<f32x4*>(wr + ((1 ^ rot) << 2)) = t;
        t.lo = acc[3][0]; t.hi = acc[3][1];
        *reinterpret_cast<f32x4*>(wr + 640 + ((0 ^ rot) << 2)) = t;
        t.lo = acc[3][2]; t.hi = acc[3][3];
        *reinterpret_cast<f32x4*>(wr + 640 + ((1 ^ rot) << 2)) = t;
    }
    asm volatile("s_waitcnt lgkmcnt(0)" ::: "memory");
    __builtin_amdgcn_sched_barrier(0);
    if (lane >= 32) {
        const float* r0 = sw + (bwl - 2) * 640 + (m * 16 + s8) * 20;
        const float* r1 = r0 + 160;
        #pragma unroll
        for (int qq = 0; qq < 4; qq++) {
            f32x4 u0 = *reinterpret_cast<const f32x4*>(r0 + qq * 4);
            f32x4 u1 = *reinterpret_cast<const f32x4*>(r1 + qq * 4);
            a0[qq*4+0] = u0.x; a0[qq*4+1] = u0.y; a0[qq*4+2] = u0.z; a0[qq*4+3] = u0.w;
            a1[qq*4+0] = u1.x; a1[qq*4+1] = u1.y; a1[qq*4+2] = u1.z; a1[qq*4+3] = u1.w;
        }
    }

    // ---------------- LU, implicit partial pivoting (register rows) ----------------
    unsigned active = 0xffffu;
    int inv = 0;
    float myd0 = 1.f, myd1 = 1.f;

    #pragma unroll
    for (int k = 0; k < 16; k++) {
        const unsigned act0 = (active >> s8) & 1u;
        const unsigned act1 = (active >> (s8 + 8)) & 1u;
        float av = act0 ? fabsf(a0[k]) : -1.f;
        int idx = s8;
        {
            float av1 = act1 ? fabsf(a1[k]) : -1.f;
            if (av1 > av) { av = av1; idx = s8 + 8; }
        }
        #pragma unroll
        for (int d = 1; d < 8; d <<= 1) {
            float ov = __shfl_xor(av, d, 8);
            int   oi = __shfl_xor(idx, d, 8);
            if (ov > av || (ov == av && oi < idx)) { av = ov; idx = oi; }
        }
        const int p = idx;
        const int plane = p & 7;
        const bool phi = (p & 8) != 0;
        float psel = phi ? a1[k] : a0[k];
        const float pk = __shfl(psel, plane, 8);
        const float rcp = 1.0f / pk;

        if (s8 == p)     myd0 = pk;
        if (s8 + 8 == p) myd1 = pk;
        inv += __popc(active & ((1u << p) - 1u));
        active &= ~(1u << p);

        const float f0 = (act0 && s8 != p)       ? a0[k] * rcp : 0.f;
        const float f1 = (act1 && (s8 + 8) != p) ? a1[k] * rcp : 0.f;

        #pragma unroll
        for (int j = k + 1; j < 16; j++) {
            float sel = phi ? a1[j] : a0[j];
            float pv = __shfl(sel, plane, 8);
            a0[j] = fmaf(-f0, pv, a0[j]);
            a1[j] = fmaf(-f1, pv, a1[j]);
        }
    }

    float ld = logf(fabsf(myd0)) + logf(fabsf(myd1));
    int ng = ((myd0 < 0.f) ? 1 : 0) + ((myd1 < 0.f) ? 1 : 0);
    #pragma unroll
    for (int d = 1; d < 8; d <<= 1) {
        ld += __shfl_xor(ld, d, 8);
        ng += __shfl_xor(ng, d, 8);
    }
    const int neg = (ng + inv) & 1;

    const float ld_o  = __shfl_xor(ld, 8, 16);
    const int   neg_o = __shfl_xor(neg, 8, 16);

    if ((lane & 15) == 0 && valid) {
        out[batch]     = ld + ld_o;                                      // re plane
        out[B + batch] = 3.14159265358979323846f * (float)(neg + neg_o); // im plane
    }
}

extern "C" void kernel_launch(void* const* d_in, const int* in_sizes, int n_in,
                              void* d_out, int out_size, void* d_ws, size_t ws_size,
                              hipStream_t stream) {
    const int* nocc = (const int*)d_in[0];
    const float* W  = (const float*)d_in[1];
    float* out = (float*)d_out;
    const int B = in_sizes[0] / 128;                 // 65536
    const int blocks = (B + NB - 1) / NB;            // 2048
    backflow_kernel<<<blocks, 512, 0, stream>>>(nocc, W, out, B);
}